// Round 1
// baseline (713.599 us; speedup 1.0000x reference)
//
#include <hip/hip_runtime.h>
#include <math.h>

// ---- problem constants ----
#define NB   4
#define CINc 256
#define LLEN 1024      // H*W = 32*32
#define NHEAD 8
#define QKVOC 192      // 2*DK + DV
#define CONVOC 192     // COUT - DV
#define OHW  31

// ---- workspace float offsets ----
#define WS_SCALE 0           // 192 floats: conv weight-norm scale
#define WS_STATS 192         // 8 floats: per-batch {mean, rstd}
#define WS_PART  256         // 4096*2 floats: per-block conv partial {sum,sumsq}
#define WS_QKV   8448        // 4*192*1024 = 786432
#define WS_E     794880      // 4*8*1024*8 = 262144
#define WS_T     1057024     // 4*8*1024*1024 = 33554432  (end 34611456 floats = 138.4MB)

// K0: scale[o] = conv_g[o] / ||conv_v[o]||
__global__ void k_wnorm(const float* __restrict__ conv_v, const float* __restrict__ conv_g,
                        float* __restrict__ ws) {
    int o = blockIdx.x, t = threadIdx.x;
    const float* v = conv_v + (size_t)o * 2304;
    float s = 0.f;
    for (int i = t; i < 2304; i += 256) { float x = v[i]; s += x * x; }
    for (int off = 1; off < 64; off <<= 1) s += __shfl_xor(s, off, 64);
    __shared__ float red[4];
    if ((t & 63) == 0) red[t >> 6] = s;
    __syncthreads();
    if (t == 0) {
        float tot = red[0] + red[1] + red[2] + red[3];
        ws[WS_SCALE + o] = conv_g[o] / sqrtf(tot);
    }
}

// K1: qkv 1x1 conv (matmul).  qkv[b,o,l] = sum_c w[o,c]*x[b,c,l] + bias; q-channels pre-scaled.
__global__ __launch_bounds__(256) void k_qkv(const float* __restrict__ x,
                                             const float* __restrict__ qkv_w,
                                             const float* __restrict__ qkv_b,
                                             float* __restrict__ ws) {
    int og = blockIdx.x, b = blockIdx.y, t = threadIdx.x;
    int o0 = og * 4;
    const float* xb = x + (size_t)b * CINc * LLEN;
    float acc[4][4] = {};
    for (int c = 0; c < CINc; c++) {
        float xv[4];
#pragma unroll
        for (int k = 0; k < 4; k++) xv[k] = xb[(size_t)c * LLEN + t + 256 * k];
#pragma unroll
        for (int oo = 0; oo < 4; oo++) {
            float w = qkv_w[(size_t)(o0 + oo) * CINc + c];
#pragma unroll
            for (int k = 0; k < 4; k++) acc[oo][k] += w * xv[k];
        }
    }
#pragma unroll
    for (int oo = 0; oo < 4; oo++) {
        int o = o0 + oo;
        float bias = qkv_b[o];
        float sc = (o < 64) ? 0.35355339059327373f : 1.0f;  // DKH^-0.5 on q
#pragma unroll
        for (int k = 0; k < 4; k++)
            ws[WS_QKV + ((size_t)b * QKVOC + o) * LLEN + t + 256 * k] = (acc[oo][k] + bias) * sc;
    }
}

// K2: weight-normed 3x3 conv, padding 1, output sliced to 31x31.  2 out-channels per block.
__global__ __launch_bounds__(256) void k_conv(const float* __restrict__ x,
                                              const float* __restrict__ conv_v,
                                              const float* __restrict__ conv_b,
                                              const float* __restrict__ ws,
                                              float* __restrict__ out) {
    int b = blockIdx.y, o0 = blockIdx.x * 2, t = threadIdx.x;
    __shared__ float xs[34 * 36];     // rows -1..32 (row 33 pad), cols -1..33 (stride 36)
    for (int i = t; i < 34 * 36; i += 256) xs[i] = 0.f;
    int h = t >> 3, wq = t & 7, w0 = wq * 4;
    float acc[2][4] = {};
    const float* xb = x + (size_t)b * CINc * 1024;
    for (int c = 0; c < CINc; c++) {
        __syncthreads();
#pragma unroll
        for (int m = 0; m < 4; m++) {
            int idx = t + 256 * m;
            int r = idx >> 5, cc = idx & 31;
            xs[(r + 1) * 36 + cc + 1] = xb[(size_t)c * 1024 + idx];
        }
        __syncthreads();
        float wgt[2][9];
#pragma unroll
        for (int oo = 0; oo < 2; oo++)
#pragma unroll
            for (int k = 0; k < 9; k++) wgt[oo][k] = conv_v[((size_t)(o0 + oo) * CINc + c) * 9 + k];
#pragma unroll
        for (int dr = 0; dr < 3; dr++) {
            const float* row = &xs[(h + dr) * 36 + w0];
            float wv[6];
#pragma unroll
            for (int u = 0; u < 6; u++) wv[u] = row[u];
#pragma unroll
            for (int oo = 0; oo < 2; oo++)
#pragma unroll
                for (int dc = 0; dc < 3; dc++) {
                    float wg = wgt[oo][dr * 3 + dc];
#pragma unroll
                    for (int k = 0; k < 4; k++) acc[oo][k] += wg * wv[dc + k];
                }
        }
    }
    if (h < 31) {
#pragma unroll
        for (int oo = 0; oo < 2; oo++) {
            int o = o0 + oo;
            float sc = ws[WS_SCALE + o], bi = conv_b[o];
#pragma unroll
            for (int k = 0; k < 4; k++) {
                int w = w0 + k;
                if (w < 31)
                    out[((size_t)(b * 256 + o) * 31 + h) * 31 + w] = sc * acc[oo][k] + bi;
            }
        }
    }
}

// K3: att[b,h,i,j] = 0.5*( sum_d q[d,i]*(k[d,j] + rel_k[j-i+1023, d]) ) + 0.5*prev
__global__ __launch_bounds__(256) void k_att(const float* __restrict__ ws,
                                             const float* __restrict__ prev,
                                             const float* __restrict__ rel_k,
                                             float* __restrict__ att) {
    int it = blockIdx.x, h = blockIdx.y, b = blockIdx.z, t = threadIdx.x;
    int i0 = it * 16;
    __shared__ float qs[16][8];
    const float* qkv = ws + WS_QKV;
    if (t < 128) {
        int il = t >> 3, d = t & 7;
        qs[il][d] = qkv[((size_t)b * QKVOC + h * 8 + d) * LLEN + i0 + il];
    }
    __syncthreads();
    int j = t * 4;
    float kr[8][4];
#pragma unroll
    for (int d = 0; d < 8; d++) {
        float4 kv = *reinterpret_cast<const float4*>(
            &qkv[((size_t)b * QKVOC + 64 + h * 8 + d) * LLEN + j]);
        kr[d][0] = kv.x; kr[d][1] = kv.y; kr[d][2] = kv.z; kr[d][3] = kv.w;
    }
    for (int il = 0; il < 16; il++) {
        int i = i0 + il;
        float qv[8];
#pragma unroll
        for (int d = 0; d < 8; d++) qv[d] = qs[il][d];
        float acc[4];
#pragma unroll
        for (int k = 0; k < 4; k++) {
            int m = j + k - i + 1023;               // always in [0, 2046]
            const float* rp = rel_k + (size_t)m * 8;
            float4 ra = *reinterpret_cast<const float4*>(rp);
            float4 rb = *reinterpret_cast<const float4*>(rp + 4);
            acc[k] = qv[0] * (kr[0][k] + ra.x) + qv[1] * (kr[1][k] + ra.y)
                   + qv[2] * (kr[2][k] + ra.z) + qv[3] * (kr[3][k] + ra.w)
                   + qv[4] * (kr[4][k] + rb.x) + qv[5] * (kr[5][k] + rb.y)
                   + qv[6] * (kr[6][k] + rb.z) + qv[7] * (kr[7][k] + rb.w);
        }
        size_t off = ((size_t)(b * 8 + h) * 1024 + i) * 1024 + j;
        float4 pv = *reinterpret_cast<const float4*>(&prev[off]);
        float4 ov;
        ov.x = 0.5f * acc[0] + 0.5f * pv.x;
        ov.y = 0.5f * acc[1] + 0.5f * pv.y;
        ov.z = 0.5f * acc[2] + 0.5f * pv.z;
        ov.w = 0.5f * acc[3] + 0.5f * pv.w;
        *reinterpret_cast<float4*>(&att[off]) = ov;
    }
}

// K4: t = conv3x3(att; 8->8 head channels) + bias; per-block {sum,sumsq} partials.
__global__ __launch_bounds__(256) void k_attconv(const float* __restrict__ att,
                                                 const float* __restrict__ attc_w,
                                                 const float* __restrict__ attc_b,
                                                 float* __restrict__ ws) {
    int jt = blockIdx.x, yt = blockIdx.y, b = blockIdx.z, t = threadIdx.x;
    int j0 = jt * 128, i0 = yt * 8;
    __shared__ float xs[8][10][132];
    for (int n = 0; n < 41; n++) {
        int idx = t + 256 * n;
        if (idx < 10400) {
            int hp = idx / 1300; int rem = idx - hp * 1300;
            int r = rem / 130;   int c = rem - r * 130;
            int gi = i0 - 1 + r, gj = j0 - 1 + c;
            float v = 0.f;
            if (gi >= 0 && gi < 1024 && gj >= 0 && gj < 1024)
                v = att[((size_t)(b * 8 + hp) * 1024 + gi) * 1024 + gj];
            xs[hp][r][c] = v;
        }
    }
    int ho = t >> 5, xg = t & 31;
    float wreg[72];
#pragma unroll
    for (int u = 0; u < 72; u++) wreg[u] = attc_w[ho * 72 + u];
    float bias = attc_b[ho];
    __syncthreads();
    float ssum = 0.f, ssq = 0.f;
    for (int y = 0; y < 8; y++) {
        float acc[4] = {bias, bias, bias, bias};
#pragma unroll
        for (int hp = 0; hp < 8; hp++)
#pragma unroll
            for (int di = 0; di < 3; di++) {
                const float* row = &xs[hp][y + di][xg * 4];
                float wv[6];
#pragma unroll
                for (int u = 0; u < 6; u++) wv[u] = row[u];
#pragma unroll
                for (int dj = 0; dj < 3; dj++) {
                    float wg = wreg[(hp * 3 + di) * 3 + dj];
#pragma unroll
                    for (int k = 0; k < 4; k++) acc[k] += wg * wv[dj + k];
                }
            }
        size_t off = ((size_t)(b * 8 + ho) * 1024 + (i0 + y)) * 1024 + j0 + xg * 4;
        *reinterpret_cast<float4*>(&ws[WS_T + off]) = make_float4(acc[0], acc[1], acc[2], acc[3]);
#pragma unroll
        for (int k = 0; k < 4; k++) { ssum += acc[k]; ssq += acc[k] * acc[k]; }
    }
    for (int off = 1; off < 64; off <<= 1) {
        ssum += __shfl_xor(ssum, off, 64);
        ssq  += __shfl_xor(ssq, off, 64);
    }
    __shared__ float r1[4], r2[4];
    if ((t & 63) == 0) { r1[t >> 6] = ssum; r2[t >> 6] = ssq; }
    __syncthreads();
    if (t == 0) {
        int lin = (b * 128 + yt) * 8 + jt;
        ws[WS_PART + lin * 2]     = r1[0] + r1[1] + r1[2] + r1[3];
        ws[WS_PART + lin * 2 + 1] = r2[0] + r2[1] + r2[2] + r2[3];
    }
}

// K4b: reduce partials -> per-batch mean, rstd
__global__ void k_stats(float* __restrict__ ws) {
    int b = blockIdx.x, t = threadIdx.x;
    float S = 0.f, Q = 0.f;
    for (int n = t; n < 1024; n += 256) {
        S += ws[WS_PART + (size_t)(b * 1024 + n) * 2];
        Q += ws[WS_PART + (size_t)(b * 1024 + n) * 2 + 1];
    }
    for (int off = 1; off < 64; off <<= 1) { S += __shfl_xor(S, off, 64); Q += __shfl_xor(Q, off, 64); }
    __shared__ float r1[4], r2[4];
    if ((t & 63) == 0) { r1[t >> 6] = S; r2[t >> 6] = Q; }
    __syncthreads();
    if (t == 0) {
        float Sa = r1[0] + r1[1] + r1[2] + r1[3];
        float Qa = r2[0] + r2[1] + r2[2] + r2[3];
        float N = 8.0f * 1024.f * 1024.f;
        float mean = Sa / N;
        float var = Qa / N - mean * mean;
        ws[WS_STATS + b * 2]     = mean;
        ws[WS_STATS + b * 2 + 1] = 1.0f / sqrtf(var + 1e-5f);
    }
}

// K5: per-row: normalize t + leaky + mix -> logits (in-place over att), softmax, PV -> E
__global__ __launch_bounds__(256) void k_final(float* __restrict__ logits,
                                               const float* __restrict__ gn_w,
                                               const float* __restrict__ gn_b,
                                               float* __restrict__ ws) {
    int row = blockIdx.x;                       // (b*8+h)*1024 + i
    int b = row >> 13, h = (row >> 10) & 7;
    int t = threadIdx.x;
    float mean = ws[WS_STATS + b * 2], rstd = ws[WS_STATS + b * 2 + 1];
    float gw = gn_w[h], gb = gn_b[h];
    size_t roff = (size_t)row * 1024 + t * 4;
    float4 tv = *reinterpret_cast<const float4*>(&ws[WS_T + roff]);
    float4 av = *reinterpret_cast<const float4*>(&logits[roff]);
    float lg[4];
    {
        float tt[4] = {tv.x, tv.y, tv.z, tv.w};
        float aa[4] = {av.x, av.y, av.z, av.w};
#pragma unroll
        for (int k = 0; k < 4; k++) {
            float xv = (tt[k] - mean) * rstd * gw + gb;
            xv = (xv >= 0.f) ? xv : 0.01f * xv;
            lg[k] = 0.5f * xv + 0.5f * aa[k];
        }
    }
    *reinterpret_cast<float4*>(&logits[roff]) = make_float4(lg[0], lg[1], lg[2], lg[3]);
    // softmax over the 1024-row
    float m = fmaxf(fmaxf(lg[0], lg[1]), fmaxf(lg[2], lg[3]));
    for (int off = 1; off < 64; off <<= 1) m = fmaxf(m, __shfl_xor(m, off, 64));
    __shared__ float red[4], red2[4], redE[4][8];
    int wvi = t >> 6, ln = t & 63;
    if (ln == 0) red[wvi] = m;
    __syncthreads();
    m = fmaxf(fmaxf(red[0], red[1]), fmaxf(red[2], red[3]));
    float e[4]; float s = 0.f;
#pragma unroll
    for (int k = 0; k < 4; k++) { e[k] = __expf(lg[k] - m); s += e[k]; }
    for (int off = 1; off < 64; off <<= 1) s += __shfl_xor(s, off, 64);
    if (ln == 0) red2[wvi] = s;
    __syncthreads();
    s = red2[0] + red2[1] + red2[2] + red2[3];
    // PV: E[d] = (sum_j e_j * v[d][j]) / s
    const float* vbase = ws + WS_QKV + ((size_t)b * QKVOC + 128 + h * 8) * LLEN + t * 4;
    float acc[8];
#pragma unroll
    for (int d = 0; d < 8; d++) {
        float4 vv = *reinterpret_cast<const float4*>(vbase + (size_t)d * LLEN);
        acc[d] = e[0] * vv.x + e[1] * vv.y + e[2] * vv.z + e[3] * vv.w;
    }
#pragma unroll
    for (int d = 0; d < 8; d++)
        for (int off = 1; off < 64; off <<= 1) acc[d] += __shfl_xor(acc[d], off, 64);
    if (ln == 0) {
#pragma unroll
        for (int d = 0; d < 8; d++) redE[wvi][d] = acc[d];
    }
    __syncthreads();
    if (t < 8) {
        float tot = redE[0][t] + redE[1][t] + redE[2][t] + redE[3][t];
        ws[WS_E + (size_t)row * 8 + t] = tot / s;
    }
}

// K6: scatter E -> attn output region with the reference's reshape quirk + 31x31 slice
__global__ void k_scatter(const float* __restrict__ ws, float* __restrict__ out) {
    int idx = blockIdx.x * 256 + threadIdx.x;
    if (idx >= 4 * 64 * 31 * 31) return;
    int x = idx % 31; int rest = idx / 31;
    int y = rest % 31; rest /= 31;
    int hd = rest % 64; int b = rest / 64;
    int h = hd >> 3, d = hd & 7;
    int flat = d * 1024 + y * 32 + x;
    int lp = flat >> 3, mp = flat & 7;
    float v = ws[WS_E + ((size_t)(b * 8 + h) * 1024 + lp) * 8 + mp];
    out[((size_t)(b * 256 + 192 + hd) * 31 + y) * 31 + x] = v;
}

extern "C" void kernel_launch(void* const* d_in, const int* in_sizes, int n_in,
                              void* d_out, int out_size, void* d_ws, size_t ws_size,
                              hipStream_t stream) {
    (void)in_sizes; (void)n_in; (void)out_size; (void)ws_size;
    const float* x      = (const float*)d_in[0];
    const float* prev   = (const float*)d_in[1];
    const float* conv_v = (const float*)d_in[2];
    const float* conv_g = (const float*)d_in[3];
    const float* conv_b = (const float*)d_in[4];
    const float* qkv_w  = (const float*)d_in[5];
    const float* qkv_b  = (const float*)d_in[6];
    const float* attc_w = (const float*)d_in[7];
    const float* attc_b = (const float*)d_in[8];
    const float* gn_w   = (const float*)d_in[9];
    const float* gn_b   = (const float*)d_in[10];
    const float* rel_k  = (const float*)d_in[11];
    float* out = (float*)d_out;
    float* ws  = (float*)d_ws;
    float* logits = out + 984064;   // att_matrix lives here, overwritten in-place by K5

    k_wnorm<<<192, 256, 0, stream>>>(conv_v, conv_g, ws);
    k_qkv<<<dim3(48, 4), 256, 0, stream>>>(x, qkv_w, qkv_b, ws);
    k_conv<<<dim3(96, 4), 256, 0, stream>>>(x, conv_v, conv_b, ws, out);
    k_att<<<dim3(64, 8, 4), 256, 0, stream>>>(ws, prev, rel_k, logits);
    k_attconv<<<dim3(8, 128, 4), 256, 0, stream>>>(logits, attc_w, attc_b, ws);
    k_stats<<<4, 256, 0, stream>>>(ws);
    k_final<<<32768, 256, 0, stream>>>(logits, gn_w, gn_b, ws);
    k_scatter<<<961, 256, 0, stream>>>(ws, out);
}

// Round 2
// 551.516 us; speedup vs baseline: 1.2939x; 1.2939x over previous
//
#include <hip/hip_runtime.h>
#include <math.h>

// ---- problem constants ----
#define NB   4
#define CINc 256
#define LLEN 1024      // H*W = 32*32
#define NHEAD 8
#define QKVOC 192      // 2*DK + DV
#define CONVOC 192     // COUT - DV
#define OHW  31

// ---- workspace float offsets ----
#define WS_SCALE 0           // 192 floats: conv weight-norm scale
#define WS_STATS 192         // 8 floats: per-batch {mean, rstd}
#define WS_PART  256         // 4096*2 floats: per-block conv partial {sum,sumsq}
#define WS_QKV   8448        // 4*192*1024 = 786432
#define WS_E     794880      // 4*8*1024*8 = 262144
#define WS_T     1057024     // 4*8*1024*1024 = 33554432  (end 34611456 floats = 138.4MB)

// K0: scale[o] = conv_g[o] / ||conv_v[o]||
__global__ void k_wnorm(const float* __restrict__ conv_v, const float* __restrict__ conv_g,
                        float* __restrict__ ws) {
    int o = blockIdx.x, t = threadIdx.x;
    const float* v = conv_v + (size_t)o * 2304;
    float s = 0.f;
    for (int i = t; i < 2304; i += 256) { float x = v[i]; s += x * x; }
    for (int off = 1; off < 64; off <<= 1) s += __shfl_xor(s, off, 64);
    __shared__ float red[4];
    if ((t & 63) == 0) red[t >> 6] = s;
    __syncthreads();
    if (t == 0) {
        float tot = red[0] + red[1] + red[2] + red[3];
        ws[WS_SCALE + o] = conv_g[o] / sqrtf(tot);
    }
}

// K1: qkv 1x1 conv (matmul).  qkv[b,o,l] = sum_c w[o,c]*x[b,c,l] + bias; q-channels pre-scaled.
__global__ __launch_bounds__(256) void k_qkv(const float* __restrict__ x,
                                             const float* __restrict__ qkv_w,
                                             const float* __restrict__ qkv_b,
                                             float* __restrict__ ws) {
    int og = blockIdx.x, b = blockIdx.y, t = threadIdx.x;
    int o0 = og * 4;
    const float* xb = x + (size_t)b * CINc * LLEN;
    float acc[4][4] = {};
    for (int c = 0; c < CINc; c++) {
        float xv[4];
#pragma unroll
        for (int k = 0; k < 4; k++) xv[k] = xb[(size_t)c * LLEN + t + 256 * k];
#pragma unroll
        for (int oo = 0; oo < 4; oo++) {
            float w = qkv_w[(size_t)(o0 + oo) * CINc + c];
#pragma unroll
            for (int k = 0; k < 4; k++) acc[oo][k] += w * xv[k];
        }
    }
#pragma unroll
    for (int oo = 0; oo < 4; oo++) {
        int o = o0 + oo;
        float bias = qkv_b[o];
        float sc = (o < 64) ? 0.35355339059327373f : 1.0f;  // DKH^-0.5 on q
#pragma unroll
        for (int k = 0; k < 4; k++)
            ws[WS_QKV + ((size_t)b * QKVOC + o) * LLEN + t + 256 * k] = (acc[oo][k] + bias) * sc;
    }
}

// K2: weight-normed 3x3 conv, padding 1, output sliced to 31x31.  2 out-channels per block.
__global__ __launch_bounds__(256) void k_conv(const float* __restrict__ x,
                                              const float* __restrict__ conv_v,
                                              const float* __restrict__ conv_b,
                                              const float* __restrict__ ws,
                                              float* __restrict__ out) {
    int b = blockIdx.y, o0 = blockIdx.x * 2, t = threadIdx.x;
    __shared__ float xs[34 * 36];     // rows -1..32 (row 33 pad), cols -1..33 (stride 36)
    for (int i = t; i < 34 * 36; i += 256) xs[i] = 0.f;
    int h = t >> 3, wq = t & 7, w0 = wq * 4;
    float acc[2][4] = {};
    const float* xb = x + (size_t)b * CINc * 1024;
    for (int c = 0; c < CINc; c++) {
        __syncthreads();
#pragma unroll
        for (int m = 0; m < 4; m++) {
            int idx = t + 256 * m;
            int r = idx >> 5, cc = idx & 31;
            xs[(r + 1) * 36 + cc + 1] = xb[(size_t)c * 1024 + idx];
        }
        __syncthreads();
        float wgt[2][9];
#pragma unroll
        for (int oo = 0; oo < 2; oo++)
#pragma unroll
            for (int k = 0; k < 9; k++) wgt[oo][k] = conv_v[((size_t)(o0 + oo) * CINc + c) * 9 + k];
#pragma unroll
        for (int dr = 0; dr < 3; dr++) {
            const float* row = &xs[(h + dr) * 36 + w0];
            float wv[6];
#pragma unroll
            for (int u = 0; u < 6; u++) wv[u] = row[u];
#pragma unroll
            for (int oo = 0; oo < 2; oo++)
#pragma unroll
                for (int dc = 0; dc < 3; dc++) {
                    float wg = wgt[oo][dr * 3 + dc];
#pragma unroll
                    for (int k = 0; k < 4; k++) acc[oo][k] += wg * wv[dc + k];
                }
        }
    }
    if (h < 31) {
#pragma unroll
        for (int oo = 0; oo < 2; oo++) {
            int o = o0 + oo;
            float sc = ws[WS_SCALE + o], bi = conv_b[o];
#pragma unroll
            for (int k = 0; k < 4; k++) {
                int w = w0 + k;
                if (w < 31)
                    out[((size_t)(b * 256 + o) * 31 + h) * 31 + w] = sc * acc[oo][k] + bi;
            }
        }
    }
}

// K3: att[b,h,i,j] = 0.5*( sum_d q[d,i]*(k[d,j] + rel_k[j-i+1023, d]) ) + 0.5*prev
__global__ __launch_bounds__(256) void k_att(const float* __restrict__ ws,
                                             const float* __restrict__ prev,
                                             const float* __restrict__ rel_k,
                                             float* __restrict__ att) {
    int it = blockIdx.x, h = blockIdx.y, b = blockIdx.z, t = threadIdx.x;
    int i0 = it * 16;
    __shared__ float qs[16][8];
    const float* qkv = ws + WS_QKV;
    if (t < 128) {
        int il = t >> 3, d = t & 7;
        qs[il][d] = qkv[((size_t)b * QKVOC + h * 8 + d) * LLEN + i0 + il];
    }
    __syncthreads();
    int j = t * 4;
    float kr[8][4];
#pragma unroll
    for (int d = 0; d < 8; d++) {
        float4 kv = *reinterpret_cast<const float4*>(
            &qkv[((size_t)b * QKVOC + 64 + h * 8 + d) * LLEN + j]);
        kr[d][0] = kv.x; kr[d][1] = kv.y; kr[d][2] = kv.z; kr[d][3] = kv.w;
    }
    for (int il = 0; il < 16; il++) {
        int i = i0 + il;
        float qv[8];
#pragma unroll
        for (int d = 0; d < 8; d++) qv[d] = qs[il][d];
        float acc[4];
#pragma unroll
        for (int k = 0; k < 4; k++) {
            int m = j + k - i + 1023;               // always in [0, 2046]
            const float* rp = rel_k + (size_t)m * 8;
            float4 ra = *reinterpret_cast<const float4*>(rp);
            float4 rb = *reinterpret_cast<const float4*>(rp + 4);
            acc[k] = qv[0] * (kr[0][k] + ra.x) + qv[1] * (kr[1][k] + ra.y)
                   + qv[2] * (kr[2][k] + ra.z) + qv[3] * (kr[3][k] + ra.w)
                   + qv[4] * (kr[4][k] + rb.x) + qv[5] * (kr[5][k] + rb.y)
                   + qv[6] * (kr[6][k] + rb.z) + qv[7] * (kr[7][k] + rb.w);
        }
        size_t off = ((size_t)(b * 8 + h) * 1024 + i) * 1024 + j;
        float4 pv = *reinterpret_cast<const float4*>(&prev[off]);
        float4 ov;
        ov.x = 0.5f * acc[0] + 0.5f * pv.x;
        ov.y = 0.5f * acc[1] + 0.5f * pv.y;
        ov.z = 0.5f * acc[2] + 0.5f * pv.z;
        ov.w = 0.5f * acc[3] + 0.5f * pv.w;
        *reinterpret_cast<float4*>(&att[off]) = ov;
    }
}

// K4 (rewritten): LDS-free att-conv.  Thread (y, cg) computes 1 row x 4 cols x all
// 8 output heads.  Row data via aligned global float4 (L1/L2-hot) + 2 cross-lane
// shuffles for the +-1 column halo; edge lanes (cg==0/31) fetch the halo scalar.
// No staging LDS -> zero bank conflicts; VALU-bound at ~2304 FMA/thread.
__global__ __launch_bounds__(256) void k_attconv(const float* __restrict__ att,
                                                 const float* __restrict__ attc_w,
                                                 const float* __restrict__ attc_b,
                                                 float* __restrict__ ws) {
    int jt = blockIdx.x, it = blockIdx.y, b = blockIdx.z, t = threadIdx.x;
    int j0 = jt * 128, i0 = it * 8;
    int y = t >> 5, cg = t & 31;
    int orow = i0 + y;                       // output row in [0,1024)
    float acc[8][4] = {};
#pragma unroll 1
    for (int hp = 0; hp < 8; hp++) {
        const float* plane = att + (((size_t)(b * 8 + hp)) << 20);
#pragma unroll
        for (int di = 0; di < 3; di++) {
            int r = orow - 1 + di;
            bool rok = (r >= 0 && r < 1024);
            const float* rowp = plane + ((size_t)(r < 0 ? 0 : r) << 10) + j0;
            float4 v = make_float4(0.f, 0.f, 0.f, 0.f);
            if (rok) v = *reinterpret_cast<const float4*>(rowp + cg * 4);
            float ls = __shfl_up(v.w, 1, 64);
            float rs = __shfl_down(v.x, 1, 64);
            if (cg == 0)  ls = (rok && j0 > 0)          ? rowp[-1]  : 0.f;
            if (cg == 31) rs = (rok && (j0 + 128) < 1024) ? rowp[128] : 0.f;
            float w[6];
            w[0] = ls; w[1] = v.x; w[2] = v.y; w[3] = v.z; w[4] = v.w; w[5] = rs;
            // weights for (all ho, this hp, this di): 24 scalars (uniform -> SGPR)
#pragma unroll
            for (int dj = 0; dj < 3; dj++)
#pragma unroll
                for (int ho = 0; ho < 8; ho++) {
                    float wg = attc_w[ho * 72 + hp * 9 + di * 3 + dj];
#pragma unroll
                    for (int k = 0; k < 4; k++) acc[ho][k] += wg * w[dj + k];
                }
        }
    }
    // bias, store, per-block stats
    float ssum = 0.f, ssq = 0.f;
#pragma unroll
    for (int ho = 0; ho < 8; ho++) {
        float bi = attc_b[ho];
        float4 o;
        o.x = acc[ho][0] + bi; o.y = acc[ho][1] + bi;
        o.z = acc[ho][2] + bi; o.w = acc[ho][3] + bi;
        ssum += o.x + o.y + o.z + o.w;
        ssq  += o.x * o.x + o.y * o.y + o.z * o.z + o.w * o.w;
        size_t off = (((size_t)(b * 8 + ho) * 1024 + orow) << 10) + j0 + cg * 4;
        *reinterpret_cast<float4*>(&ws[WS_T + off]) = o;
    }
    for (int off = 1; off < 64; off <<= 1) {
        ssum += __shfl_xor(ssum, off, 64);
        ssq  += __shfl_xor(ssq, off, 64);
    }
    __shared__ float r1[4], r2[4];
    if ((t & 63) == 0) { r1[t >> 6] = ssum; r2[t >> 6] = ssq; }
    __syncthreads();
    if (t == 0) {
        int lin = (b * 128 + it) * 8 + jt;
        ws[WS_PART + lin * 2]     = r1[0] + r1[1] + r1[2] + r1[3];
        ws[WS_PART + lin * 2 + 1] = r2[0] + r2[1] + r2[2] + r2[3];
    }
}

// K4b: reduce partials -> per-batch mean, rstd
__global__ void k_stats(float* __restrict__ ws) {
    int b = blockIdx.x, t = threadIdx.x;
    float S = 0.f, Q = 0.f;
    for (int n = t; n < 1024; n += 256) {
        S += ws[WS_PART + (size_t)(b * 1024 + n) * 2];
        Q += ws[WS_PART + (size_t)(b * 1024 + n) * 2 + 1];
    }
    for (int off = 1; off < 64; off <<= 1) { S += __shfl_xor(S, off, 64); Q += __shfl_xor(Q, off, 64); }
    __shared__ float r1[4], r2[4];
    if ((t & 63) == 0) { r1[t >> 6] = S; r2[t >> 6] = Q; }
    __syncthreads();
    if (t == 0) {
        float Sa = r1[0] + r1[1] + r1[2] + r1[3];
        float Qa = r2[0] + r2[1] + r2[2] + r2[3];
        float N = 8.0f * 1024.f * 1024.f;
        float mean = Sa / N;
        float var = Qa / N - mean * mean;
        ws[WS_STATS + b * 2]     = mean;
        ws[WS_STATS + b * 2 + 1] = 1.0f / sqrtf(var + 1e-5f);
    }
}

// K5: per-row: normalize t + leaky + mix -> logits (in-place over att), softmax, PV -> E
__global__ __launch_bounds__(256) void k_final(float* __restrict__ logits,
                                               const float* __restrict__ gn_w,
                                               const float* __restrict__ gn_b,
                                               float* __restrict__ ws) {
    int row = blockIdx.x;                       // (b*8+h)*1024 + i
    int b = row >> 13, h = (row >> 10) & 7;
    int t = threadIdx.x;
    float mean = ws[WS_STATS + b * 2], rstd = ws[WS_STATS + b * 2 + 1];
    float gw = gn_w[h], gb = gn_b[h];
    size_t roff = (size_t)row * 1024 + t * 4;
    float4 tv = *reinterpret_cast<const float4*>(&ws[WS_T + roff]);
    float4 av = *reinterpret_cast<const float4*>(&logits[roff]);
    float lg[4];
    {
        float tt[4] = {tv.x, tv.y, tv.z, tv.w};
        float aa[4] = {av.x, av.y, av.z, av.w};
#pragma unroll
        for (int k = 0; k < 4; k++) {
            float xv = (tt[k] - mean) * rstd * gw + gb;
            xv = (xv >= 0.f) ? xv : 0.01f * xv;
            lg[k] = 0.5f * xv + 0.5f * aa[k];
        }
    }
    *reinterpret_cast<float4*>(&logits[roff]) = make_float4(lg[0], lg[1], lg[2], lg[3]);
    // softmax over the 1024-row
    float m = fmaxf(fmaxf(lg[0], lg[1]), fmaxf(lg[2], lg[3]));
    for (int off = 1; off < 64; off <<= 1) m = fmaxf(m, __shfl_xor(m, off, 64));
    __shared__ float red[4], red2[4], redE[4][8];
    int wvi = t >> 6, ln = t & 63;
    if (ln == 0) red[wvi] = m;
    __syncthreads();
    m = fmaxf(fmaxf(red[0], red[1]), fmaxf(red[2], red[3]));
    float e[4]; float s = 0.f;
#pragma unroll
    for (int k = 0; k < 4; k++) { e[k] = __expf(lg[k] - m); s += e[k]; }
    for (int off = 1; off < 64; off <<= 1) s += __shfl_xor(s, off, 64);
    if (ln == 0) red2[wvi] = s;
    __syncthreads();
    s = red2[0] + red2[1] + red2[2] + red2[3];
    // PV: E[d] = (sum_j e_j * v[d][j]) / s
    const float* vbase = ws + WS_QKV + ((size_t)b * QKVOC + 128 + h * 8) * LLEN + t * 4;
    float acc[8];
#pragma unroll
    for (int d = 0; d < 8; d++) {
        float4 vv = *reinterpret_cast<const float4*>(vbase + (size_t)d * LLEN);
        acc[d] = e[0] * vv.x + e[1] * vv.y + e[2] * vv.z + e[3] * vv.w;
    }
#pragma unroll
    for (int d = 0; d < 8; d++)
        for (int off = 1; off < 64; off <<= 1) acc[d] += __shfl_xor(acc[d], off, 64);
    if (ln == 0) {
#pragma unroll
        for (int d = 0; d < 8; d++) redE[wvi][d] = acc[d];
    }
    __syncthreads();
    if (t < 8) {
        float tot = redE[0][t] + redE[1][t] + redE[2][t] + redE[3][t];
        ws[WS_E + (size_t)row * 8 + t] = tot / s;
    }
}

// K6: scatter E -> attn output region with the reference's reshape quirk + 31x31 slice
__global__ void k_scatter(const float* __restrict__ ws, float* __restrict__ out) {
    int idx = blockIdx.x * 256 + threadIdx.x;
    if (idx >= 4 * 64 * 31 * 31) return;
    int x = idx % 31; int rest = idx / 31;
    int y = rest % 31; rest /= 31;
    int hd = rest % 64; int b = rest / 64;
    int h = hd >> 3, d = hd & 7;
    int flat = d * 1024 + y * 32 + x;
    int lp = flat >> 3, mp = flat & 7;
    float v = ws[WS_E + ((size_t)(b * 8 + h) * 1024 + lp) * 8 + mp];
    out[((size_t)(b * 256 + 192 + hd) * 31 + y) * 31 + x] = v;
}

extern "C" void kernel_launch(void* const* d_in, const int* in_sizes, int n_in,
                              void* d_out, int out_size, void* d_ws, size_t ws_size,
                              hipStream_t stream) {
    (void)in_sizes; (void)n_in; (void)out_size; (void)ws_size;
    const float* x      = (const float*)d_in[0];
    const float* prev   = (const float*)d_in[1];
    const float* conv_v = (const float*)d_in[2];
    const float* conv_g = (const float*)d_in[3];
    const float* conv_b = (const float*)d_in[4];
    const float* qkv_w  = (const float*)d_in[5];
    const float* qkv_b  = (const float*)d_in[6];
    const float* attc_w = (const float*)d_in[7];
    const float* attc_b = (const float*)d_in[8];
    const float* gn_w   = (const float*)d_in[9];
    const float* gn_b   = (const float*)d_in[10];
    const float* rel_k  = (const float*)d_in[11];
    float* out = (float*)d_out;
    float* ws  = (float*)d_ws;
    float* logits = out + 984064;   // att_matrix lives here, overwritten in-place by K5

    k_wnorm<<<192, 256, 0, stream>>>(conv_v, conv_g, ws);
    k_qkv<<<dim3(48, 4), 256, 0, stream>>>(x, qkv_w, qkv_b, ws);
    k_conv<<<dim3(96, 4), 256, 0, stream>>>(x, conv_v, conv_b, ws, out);
    k_att<<<dim3(64, 8, 4), 256, 0, stream>>>(ws, prev, rel_k, logits);
    k_attconv<<<dim3(8, 128, 4), 256, 0, stream>>>(logits, attc_w, attc_b, ws);
    k_stats<<<4, 256, 0, stream>>>(ws);
    k_final<<<32768, 256, 0, stream>>>(logits, gn_w, gn_b, ws);
    k_scatter<<<961, 256, 0, stream>>>(ws, out);
}

// Round 3
// 462.029 us; speedup vs baseline: 1.5445x; 1.1937x over previous
//
#include <hip/hip_runtime.h>
#include <math.h>

// ---- problem constants ----
#define NB   4
#define CINc 256
#define LLEN 1024      // H*W = 32*32
#define NHEAD 8
#define QKVOC 192      // 2*DK + DV
#define CONVOC 192     // COUT - DV
#define OHW  31

// ---- workspace float offsets ----
#define WS_SCALE 0           // 192 floats: conv weight-norm scale
#define WS_STATS 192         // 8 floats: per-batch {mean, rstd}
#define WS_PART  256         // 4096*2 floats: per-block conv partial {sum,sumsq}
#define WS_QKV   8448        // 4*192*1024 = 786432
#define WS_E     794880      // 4*8*1024*8 = 262144
#define WS_T     1057024     // 4*8*1024*1024 = 33554432  (end 34611456 floats = 138.4MB)

// K0: scale[o] = conv_g[o] / ||conv_v[o]||
__global__ void k_wnorm(const float* __restrict__ conv_v, const float* __restrict__ conv_g,
                        float* __restrict__ ws) {
    int o = blockIdx.x, t = threadIdx.x;
    const float* v = conv_v + (size_t)o * 2304;
    float s = 0.f;
    for (int i = t; i < 2304; i += 256) { float x = v[i]; s += x * x; }
    for (int off = 1; off < 64; off <<= 1) s += __shfl_xor(s, off, 64);
    __shared__ float red[4];
    if ((t & 63) == 0) red[t >> 6] = s;
    __syncthreads();
    if (t == 0) {
        float tot = red[0] + red[1] + red[2] + red[3];
        ws[WS_SCALE + o] = conv_g[o] / sqrtf(tot);
    }
}

// K1: qkv 1x1 conv (matmul).  qkv[b,o,l] = sum_c w[o,c]*x[b,c,l] + bias; q-channels pre-scaled.
__global__ __launch_bounds__(256) void k_qkv(const float* __restrict__ x,
                                             const float* __restrict__ qkv_w,
                                             const float* __restrict__ qkv_b,
                                             float* __restrict__ ws) {
    int og = blockIdx.x, b = blockIdx.y, t = threadIdx.x;
    int o0 = og * 4;
    const float* xb = x + (size_t)b * CINc * LLEN;
    float acc[4][4] = {};
    for (int c = 0; c < CINc; c++) {
        float xv[4];
#pragma unroll
        for (int k = 0; k < 4; k++) xv[k] = xb[(size_t)c * LLEN + t + 256 * k];
#pragma unroll
        for (int oo = 0; oo < 4; oo++) {
            float w = qkv_w[(size_t)(o0 + oo) * CINc + c];
#pragma unroll
            for (int k = 0; k < 4; k++) acc[oo][k] += w * xv[k];
        }
    }
#pragma unroll
    for (int oo = 0; oo < 4; oo++) {
        int o = o0 + oo;
        float bias = qkv_b[o];
        float sc = (o < 64) ? 0.35355339059327373f : 1.0f;  // DKH^-0.5 on q
#pragma unroll
        for (int k = 0; k < 4; k++)
            ws[WS_QKV + ((size_t)b * QKVOC + o) * LLEN + t + 256 * k] = (acc[oo][k] + bias) * sc;
    }
}

// K2: weight-normed 3x3 conv, padding 1, output sliced to 31x31.  2 out-channels per block.
__global__ __launch_bounds__(256) void k_conv(const float* __restrict__ x,
                                              const float* __restrict__ conv_v,
                                              const float* __restrict__ conv_b,
                                              const float* __restrict__ ws,
                                              float* __restrict__ out) {
    int b = blockIdx.y, o0 = blockIdx.x * 2, t = threadIdx.x;
    __shared__ float xs[34 * 36];     // rows -1..32 (row 33 pad), cols -1..33 (stride 36)
    for (int i = t; i < 34 * 36; i += 256) xs[i] = 0.f;
    int h = t >> 3, wq = t & 7, w0 = wq * 4;
    float acc[2][4] = {};
    const float* xb = x + (size_t)b * CINc * 1024;
    for (int c = 0; c < CINc; c++) {
        __syncthreads();
#pragma unroll
        for (int m = 0; m < 4; m++) {
            int idx = t + 256 * m;
            int r = idx >> 5, cc = idx & 31;
            xs[(r + 1) * 36 + cc + 1] = xb[(size_t)c * 1024 + idx];
        }
        __syncthreads();
        float wgt[2][9];
#pragma unroll
        for (int oo = 0; oo < 2; oo++)
#pragma unroll
            for (int k = 0; k < 9; k++) wgt[oo][k] = conv_v[((size_t)(o0 + oo) * CINc + c) * 9 + k];
#pragma unroll
        for (int dr = 0; dr < 3; dr++) {
            const float* row = &xs[(h + dr) * 36 + w0];
            float wv[6];
#pragma unroll
            for (int u = 0; u < 6; u++) wv[u] = row[u];
#pragma unroll
            for (int oo = 0; oo < 2; oo++)
#pragma unroll
                for (int dc = 0; dc < 3; dc++) {
                    float wg = wgt[oo][dr * 3 + dc];
#pragma unroll
                    for (int k = 0; k < 4; k++) acc[oo][k] += wg * wv[dc + k];
                }
        }
    }
    if (h < 31) {
#pragma unroll
        for (int oo = 0; oo < 2; oo++) {
            int o = o0 + oo;
            float sc = ws[WS_SCALE + o], bi = conv_b[o];
#pragma unroll
            for (int k = 0; k < 4; k++) {
                int w = w0 + k;
                if (w < 31)
                    out[((size_t)(b * 256 + o) * 31 + h) * 31 + w] = sc * acc[oo][k] + bi;
            }
        }
    }
}

// K3 (rewritten, tiled): att[b,h,i,j] = 0.5*( qk + rel ) + 0.5*prev.
// Block = 32i x 128j tile of one (b,h).  K-tile + transposed Q-tile in LDS;
// each thread owns a 4x4 register subtile.  rel needs only 7 diagonal rows of
// rel_k per thread (reused 16x, aligned float4 pairs from L1) instead of 128
// scattered gathers -> latency amortized, VALU/HBM bound.
__global__ __launch_bounds__(256, 4) void k_att(const float* __restrict__ ws_,
                                                const float* __restrict__ prev,
                                                const float* __restrict__ rel_k,
                                                float* __restrict__ att) {
    int jt = blockIdx.x, it = blockIdx.y, bh = blockIdx.z;
    int b = bh >> 3, h = bh & 7;
    int t = threadIdx.x;
    int i0 = it * 32, j0 = jt * 128;
    __shared__ float kS[8][128];
    __shared__ float qS[32][8];
    const float* qkv = ws_ + WS_QKV;
    const float* qplane = qkv + ((size_t)b * QKVOC + h * 8) * LLEN;       // q[d][i]
    const float* kplane = qkv + ((size_t)b * QKVOC + 64 + h * 8) * LLEN;  // k[d][j]
    {   // stage K tile: 256 float4
        int d = t >> 5, jc = (t & 31) * 4;
        *reinterpret_cast<float4*>(&kS[d][jc]) =
            *reinterpret_cast<const float4*>(&kplane[(size_t)d * LLEN + j0 + jc]);
    }
    {   // stage Q tile transposed: qS[i][d]
        int i = t >> 3, d = t & 7;
        qS[i][d] = qplane[(size_t)d * LLEN + i0 + i];
    }
    __syncthreads();

    int ig = t >> 5, tj = t & 31;          // ig: i-subgroup 0..7, tj: j-group 0..31
    // load this thread's 4 q rows (8 d each)
    float qr[4][8];
#pragma unroll
    for (int ii = 0; ii < 4; ii++) {
        float4 a = *reinterpret_cast<const float4*>(&qS[ig * 4 + ii][0]);
        float4 c = *reinterpret_cast<const float4*>(&qS[ig * 4 + ii][4]);
        qr[ii][0] = a.x; qr[ii][1] = a.y; qr[ii][2] = a.z; qr[ii][3] = a.w;
        qr[ii][4] = c.x; qr[ii][5] = c.y; qr[ii][6] = c.z; qr[ii][7] = c.w;
    }
    float acc[4][4] = {};
    // QK^T part from LDS
#pragma unroll
    for (int d = 0; d < 8; d++) {
        float4 kv = *reinterpret_cast<const float4*>(&kS[d][tj * 4]);
#pragma unroll
        for (int ii = 0; ii < 4; ii++) {
            float qv = qr[ii][d];
            acc[ii][0] += qv * kv.x; acc[ii][1] += qv * kv.y;
            acc[ii][2] += qv * kv.z; acc[ii][3] += qv * kv.w;
        }
    }
    // rel part: diagonals dg = jj-ii in [-3,3]; global row m = j0-i0+1023 + 4*(tj-ig) + dg
    const float* rbase = rel_k + (size_t)(j0 - i0 + 1020 + 4 * (tj - ig)) * 8;
#pragma unroll
    for (int dgi = 0; dgi < 7; dgi++) {
        float4 ra = *reinterpret_cast<const float4*>(rbase + dgi * 8);
        float4 rb = *reinterpret_cast<const float4*>(rbase + dgi * 8 + 4);
#pragma unroll
        for (int ii = 0; ii < 4; ii++) {
#pragma unroll
            for (int jj = 0; jj < 4; jj++) {
                if (jj - ii + 3 == dgi) {
                    acc[ii][jj] += qr[ii][0] * ra.x + qr[ii][1] * ra.y
                                 + qr[ii][2] * ra.z + qr[ii][3] * ra.w
                                 + qr[ii][4] * rb.x + qr[ii][5] * rb.y
                                 + qr[ii][6] * rb.z + qr[ii][7] * rb.w;
                }
            }
        }
    }
    // epilogue: mix with prev, write att
#pragma unroll
    for (int ii = 0; ii < 4; ii++) {
        int i = i0 + ig * 4 + ii;
        size_t off = (((size_t)bh * 1024 + i) << 10) + j0 + tj * 4;
        float4 pv = *reinterpret_cast<const float4*>(&prev[off]);
        float4 ov;
        ov.x = 0.5f * acc[ii][0] + 0.5f * pv.x;
        ov.y = 0.5f * acc[ii][1] + 0.5f * pv.y;
        ov.z = 0.5f * acc[ii][2] + 0.5f * pv.z;
        ov.w = 0.5f * acc[ii][3] + 0.5f * pv.w;
        *reinterpret_cast<float4*>(&att[off]) = ov;
    }
}

// K4: LDS-free att-conv.  Thread (y, cg) computes 1 row x 4 cols x all 8 output
// heads.  Row data via aligned global float4 (L1/L2-hot) + 2 cross-lane shuffles
// for the +-1 column halo; edge lanes fetch the halo scalar.
__global__ __launch_bounds__(256) void k_attconv(const float* __restrict__ att,
                                                 const float* __restrict__ attc_w,
                                                 const float* __restrict__ attc_b,
                                                 float* __restrict__ ws) {
    int jt = blockIdx.x, it = blockIdx.y, b = blockIdx.z, t = threadIdx.x;
    int j0 = jt * 128, i0 = it * 8;
    int y = t >> 5, cg = t & 31;
    int orow = i0 + y;                       // output row in [0,1024)
    float acc[8][4] = {};
#pragma unroll 1
    for (int hp = 0; hp < 8; hp++) {
        const float* plane = att + (((size_t)(b * 8 + hp)) << 20);
#pragma unroll
        for (int di = 0; di < 3; di++) {
            int r = orow - 1 + di;
            bool rok = (r >= 0 && r < 1024);
            const float* rowp = plane + ((size_t)(r < 0 ? 0 : r) << 10) + j0;
            float4 v = make_float4(0.f, 0.f, 0.f, 0.f);
            if (rok) v = *reinterpret_cast<const float4*>(rowp + cg * 4);
            float ls = __shfl_up(v.w, 1, 64);
            float rs = __shfl_down(v.x, 1, 64);
            if (cg == 0)  ls = (rok && j0 > 0)            ? rowp[-1]  : 0.f;
            if (cg == 31) rs = (rok && (j0 + 128) < 1024) ? rowp[128] : 0.f;
            float w[6];
            w[0] = ls; w[1] = v.x; w[2] = v.y; w[3] = v.z; w[4] = v.w; w[5] = rs;
#pragma unroll
            for (int dj = 0; dj < 3; dj++)
#pragma unroll
                for (int ho = 0; ho < 8; ho++) {
                    float wg = attc_w[ho * 72 + hp * 9 + di * 3 + dj];
#pragma unroll
                    for (int k = 0; k < 4; k++) acc[ho][k] += wg * w[dj + k];
                }
        }
    }
    float ssum = 0.f, ssq = 0.f;
#pragma unroll
    for (int ho = 0; ho < 8; ho++) {
        float bi = attc_b[ho];
        float4 o;
        o.x = acc[ho][0] + bi; o.y = acc[ho][1] + bi;
        o.z = acc[ho][2] + bi; o.w = acc[ho][3] + bi;
        ssum += o.x + o.y + o.z + o.w;
        ssq  += o.x * o.x + o.y * o.y + o.z * o.z + o.w * o.w;
        size_t off = (((size_t)(b * 8 + ho) * 1024 + orow) << 10) + j0 + cg * 4;
        *reinterpret_cast<float4*>(&ws[WS_T + off]) = o;
    }
    for (int off = 1; off < 64; off <<= 1) {
        ssum += __shfl_xor(ssum, off, 64);
        ssq  += __shfl_xor(ssq, off, 64);
    }
    __shared__ float r1[4], r2[4];
    if ((t & 63) == 0) { r1[t >> 6] = ssum; r2[t >> 6] = ssq; }
    __syncthreads();
    if (t == 0) {
        int lin = (b * 128 + it) * 8 + jt;
        ws[WS_PART + lin * 2]     = r1[0] + r1[1] + r1[2] + r1[3];
        ws[WS_PART + lin * 2 + 1] = r2[0] + r2[1] + r2[2] + r2[3];
    }
}

// K4b: reduce partials -> per-batch mean, rstd
__global__ void k_stats(float* __restrict__ ws) {
    int b = blockIdx.x, t = threadIdx.x;
    float S = 0.f, Q = 0.f;
    for (int n = t; n < 1024; n += 256) {
        S += ws[WS_PART + (size_t)(b * 1024 + n) * 2];
        Q += ws[WS_PART + (size_t)(b * 1024 + n) * 2 + 1];
    }
    for (int off = 1; off < 64; off <<= 1) { S += __shfl_xor(S, off, 64); Q += __shfl_xor(Q, off, 64); }
    __shared__ float r1[4], r2[4];
    if ((t & 63) == 0) { r1[t >> 6] = S; r2[t >> 6] = Q; }
    __syncthreads();
    if (t == 0) {
        float Sa = r1[0] + r1[1] + r1[2] + r1[3];
        float Qa = r2[0] + r2[1] + r2[2] + r2[3];
        float N = 8.0f * 1024.f * 1024.f;
        float mean = Sa / N;
        float var = Qa / N - mean * mean;
        ws[WS_STATS + b * 2]     = mean;
        ws[WS_STATS + b * 2 + 1] = 1.0f / sqrtf(var + 1e-5f);
    }
}

// K5: per-row: normalize t + leaky + mix -> logits (in-place over att), softmax, PV -> E
__global__ __launch_bounds__(256) void k_final(float* __restrict__ logits,
                                               const float* __restrict__ gn_w,
                                               const float* __restrict__ gn_b,
                                               float* __restrict__ ws) {
    int row = blockIdx.x;                       // (b*8+h)*1024 + i
    int b = row >> 13, h = (row >> 10) & 7;
    int t = threadIdx.x;
    float mean = ws[WS_STATS + b * 2], rstd = ws[WS_STATS + b * 2 + 1];
    float gw = gn_w[h], gb = gn_b[h];
    size_t roff = (size_t)row * 1024 + t * 4;
    float4 tv = *reinterpret_cast<const float4*>(&ws[WS_T + roff]);
    float4 av = *reinterpret_cast<const float4*>(&logits[roff]);
    float lg[4];
    {
        float tt[4] = {tv.x, tv.y, tv.z, tv.w};
        float aa[4] = {av.x, av.y, av.z, av.w};
#pragma unroll
        for (int k = 0; k < 4; k++) {
            float xv = (tt[k] - mean) * rstd * gw + gb;
            xv = (xv >= 0.f) ? xv : 0.01f * xv;
            lg[k] = 0.5f * xv + 0.5f * aa[k];
        }
    }
    *reinterpret_cast<float4*>(&logits[roff]) = make_float4(lg[0], lg[1], lg[2], lg[3]);
    // softmax over the 1024-row
    float m = fmaxf(fmaxf(lg[0], lg[1]), fmaxf(lg[2], lg[3]));
    for (int off = 1; off < 64; off <<= 1) m = fmaxf(m, __shfl_xor(m, off, 64));
    __shared__ float red[4], red2[4], redE[4][8];
    int wvi = t >> 6, ln = t & 63;
    if (ln == 0) red[wvi] = m;
    __syncthreads();
    m = fmaxf(fmaxf(red[0], red[1]), fmaxf(red[2], red[3]));
    float e[4]; float s = 0.f;
#pragma unroll
    for (int k = 0; k < 4; k++) { e[k] = __expf(lg[k] - m); s += e[k]; }
    for (int off = 1; off < 64; off <<= 1) s += __shfl_xor(s, off, 64);
    if (ln == 0) red2[wvi] = s;
    __syncthreads();
    s = red2[0] + red2[1] + red2[2] + red2[3];
    // PV: E[d] = (sum_j e_j * v[d][j]) / s
    const float* vbase = ws + WS_QKV + ((size_t)b * QKVOC + 128 + h * 8) * LLEN + t * 4;
    float acc[8];
#pragma unroll
    for (int d = 0; d < 8; d++) {
        float4 vv = *reinterpret_cast<const float4*>(vbase + (size_t)d * LLEN);
        acc[d] = e[0] * vv.x + e[1] * vv.y + e[2] * vv.z + e[3] * vv.w;
    }
#pragma unroll
    for (int d = 0; d < 8; d++)
        for (int off = 1; off < 64; off <<= 1) acc[d] += __shfl_xor(acc[d], off, 64);
    if (ln == 0) {
#pragma unroll
        for (int d = 0; d < 8; d++) redE[wvi][d] = acc[d];
    }
    __syncthreads();
    if (t < 8) {
        float tot = redE[0][t] + redE[1][t] + redE[2][t] + redE[3][t];
        ws[WS_E + (size_t)row * 8 + t] = tot / s;
    }
}

// K6: scatter E -> attn output region with the reference's reshape quirk + 31x31 slice
__global__ void k_scatter(const float* __restrict__ ws, float* __restrict__ out) {
    int idx = blockIdx.x * 256 + threadIdx.x;
    if (idx >= 4 * 64 * 31 * 31) return;
    int x = idx % 31; int rest = idx / 31;
    int y = rest % 31; rest /= 31;
    int hd = rest % 64; int b = rest / 64;
    int h = hd >> 3, d = hd & 7;
    int flat = d * 1024 + y * 32 + x;
    int lp = flat >> 3, mp = flat & 7;
    float v = ws[WS_E + ((size_t)(b * 8 + h) * 1024 + lp) * 8 + mp];
    out[((size_t)(b * 256 + 192 + hd) * 31 + y) * 31 + x] = v;
}

extern "C" void kernel_launch(void* const* d_in, const int* in_sizes, int n_in,
                              void* d_out, int out_size, void* d_ws, size_t ws_size,
                              hipStream_t stream) {
    (void)in_sizes; (void)n_in; (void)out_size; (void)ws_size;
    const float* x      = (const float*)d_in[0];
    const float* prev   = (const float*)d_in[1];
    const float* conv_v = (const float*)d_in[2];
    const float* conv_g = (const float*)d_in[3];
    const float* conv_b = (const float*)d_in[4];
    const float* qkv_w  = (const float*)d_in[5];
    const float* qkv_b  = (const float*)d_in[6];
    const float* attc_w = (const float*)d_in[7];
    const float* attc_b = (const float*)d_in[8];
    const float* gn_w   = (const float*)d_in[9];
    const float* gn_b   = (const float*)d_in[10];
    const float* rel_k  = (const float*)d_in[11];
    float* out = (float*)d_out;
    float* ws  = (float*)d_ws;
    float* logits = out + 984064;   // att_matrix lives here, overwritten in-place by K5

    k_wnorm<<<192, 256, 0, stream>>>(conv_v, conv_g, ws);
    k_qkv<<<dim3(48, 4), 256, 0, stream>>>(x, qkv_w, qkv_b, ws);
    k_conv<<<dim3(96, 4), 256, 0, stream>>>(x, conv_v, conv_b, ws, out);
    k_att<<<dim3(8, 32, 32), 256, 0, stream>>>(ws, prev, rel_k, logits);
    k_attconv<<<dim3(8, 128, 4), 256, 0, stream>>>(logits, attc_w, attc_b, ws);
    k_stats<<<4, 256, 0, stream>>>(ws);
    k_final<<<32768, 256, 0, stream>>>(logits, gn_w, gn_b, ws);
    k_scatter<<<961, 256, 0, stream>>>(ws, out);
}

// Round 4
// 378.703 us; speedup vs baseline: 1.8843x; 1.2200x over previous
//
#include <hip/hip_runtime.h>
#include <math.h>

// ---- problem constants ----
#define NB   4
#define CINc 256
#define LLEN 1024      // H*W = 32*32
#define NHEAD 8
#define QKVOC 192      // 2*DK + DV
#define CONVOC 192     // COUT - DV
#define OHW  31

// ---- workspace float offsets ----
#define WS_SCALE 0           // 192 floats: conv weight-norm scale
#define WS_STATS 192         // 8 floats: per-batch {mean, rstd}
#define WS_PART  256         // 4096*2 floats: per-block conv partial {sum,sumsq}
#define WS_QKV   8448        // 4*192*1024 = 786432
#define WS_E     794880      // 4*8*1024*8 = 262144
#define WS_T     1057024     // 4*8*1024*1024 = 33554432  (end 34611456 floats = 138.4MB)
#define WS_CPART WS_T        // conv partials (6.3M floats) reuse WS_T region; consumed by
                             // k_convred before k_attconv overwrites WS_T (stream-serialized)

// K0: scale[o] = conv_g[o] / ||conv_v[o]||
__global__ void k_wnorm(const float* __restrict__ conv_v, const float* __restrict__ conv_g,
                        float* __restrict__ ws) {
    int o = blockIdx.x, t = threadIdx.x;
    const float* v = conv_v + (size_t)o * 2304;
    float s = 0.f;
    for (int i = t; i < 2304; i += 256) { float x = v[i]; s += x * x; }
    for (int off = 1; off < 64; off <<= 1) s += __shfl_xor(s, off, 64);
    __shared__ float red[4];
    if ((t & 63) == 0) red[t >> 6] = s;
    __syncthreads();
    if (t == 0) {
        float tot = red[0] + red[1] + red[2] + red[3];
        ws[WS_SCALE + o] = conv_g[o] / sqrtf(tot);
    }
}

// K1: qkv 1x1 conv (matmul).  qkv[b,o,l] = sum_c w[o,c]*x[b,c,l] + bias; q-channels pre-scaled.
__global__ __launch_bounds__(256) void k_qkv(const float* __restrict__ x,
                                             const float* __restrict__ qkv_w,
                                             const float* __restrict__ qkv_b,
                                             float* __restrict__ ws) {
    int og = blockIdx.x, b = blockIdx.y, t = threadIdx.x;
    int o0 = og * 4;
    const float* xb = x + (size_t)b * CINc * LLEN;
    float acc[4][4] = {};
    for (int c = 0; c < CINc; c++) {
        float xv[4];
#pragma unroll
        for (int k = 0; k < 4; k++) xv[k] = xb[(size_t)c * LLEN + t + 256 * k];
#pragma unroll
        for (int oo = 0; oo < 4; oo++) {
            float w = qkv_w[(size_t)(o0 + oo) * CINc + c];
#pragma unroll
            for (int k = 0; k < 4; k++) acc[oo][k] += w * xv[k];
        }
    }
#pragma unroll
    for (int oo = 0; oo < 4; oo++) {
        int o = o0 + oo;
        float bias = qkv_b[o];
        float sc = (o < 64) ? 0.35355339059327373f : 1.0f;  // DKH^-0.5 on q
#pragma unroll
        for (int k = 0; k < 4; k++)
            ws[WS_QKV + ((size_t)b * QKVOC + o) * LLEN + t + 256 * k] = (acc[oo][k] + bias) * sc;
    }
}

// K2 (rewritten): channel-split weight-normed 3x3 conv, pass 1.
// Block = (4 out-ch, 32 in-ch chunk, 1 batch), full 32x32 spatial.
// Weights pre-staged to LDS as [c][tap][4oo] float4; x tile stride-35 (bank-clean).
// Partials to WS_CPART; k_convred reduces 8 chunks + scale + bias + 31x31 slice.
__global__ __launch_bounds__(256) void k_conv(const float* __restrict__ x,
                                              const float* __restrict__ conv_v,
                                              float* __restrict__ ws) {
    int ot = blockIdx.x, z = blockIdx.y, b = blockIdx.z, t = threadIdx.x;
    int o0 = ot * 4, c0 = z * 32;
    __shared__ float xs[34 * 35];        // rows -1..32 (+1), cols -1..33 (+1), stride 35
    __shared__ float wS[32 * 9 * 4];     // [c][tap][oo]
    for (int idx = t; idx < 1152; idx += 256) {
        int oo = idx & 3, rem = idx >> 2;      // rem = c*9 + k
        int c = rem / 9, k = rem - c * 9;
        wS[idx] = conv_v[((size_t)(o0 + oo) * CINc + c0 + c) * 9 + k];
    }
    for (int i = t; i < 34 * 35; i += 256) xs[i] = 0.f;
    int h = t >> 3, wq = t & 7, w0 = wq * 4;
    const float* xb = x + ((size_t)b * CINc + c0) * 1024;
    float acc[4][4] = {};
    for (int c = 0; c < 32; c++) {
        __syncthreads();
        {   // stage x[c]: one float4 per thread, scattered scalar LDS writes (stride 35)
            int idx4 = t * 4;
            int r = idx4 >> 5, cc = idx4 & 31;
            float4 v = *reinterpret_cast<const float4*>(&xb[(size_t)c * 1024 + idx4]);
            float* dst = &xs[(r + 1) * 35 + cc + 1];
            dst[0] = v.x; dst[1] = v.y; dst[2] = v.z; dst[3] = v.w;
        }
        __syncthreads();
        float wv[3][6];
#pragma unroll
        for (int dr = 0; dr < 3; dr++)
#pragma unroll
            for (int u = 0; u < 6; u++)
                wv[dr][u] = xs[(h + dr) * 35 + w0 + u];
        const float* wp = &wS[c * 36];
#pragma unroll
        for (int dr = 0; dr < 3; dr++)
#pragma unroll
            for (int dc = 0; dc < 3; dc++) {
                float4 w4 = *reinterpret_cast<const float4*>(&wp[(dr * 3 + dc) * 4]);
#pragma unroll
                for (int px = 0; px < 4; px++) {
                    float xv = wv[dr][dc + px];
                    acc[0][px] += w4.x * xv; acc[1][px] += w4.y * xv;
                    acc[2][px] += w4.z * xv; acc[3][px] += w4.w * xv;
                }
            }
    }
#pragma unroll
    for (int oo = 0; oo < 4; oo++) {
        size_t off = WS_CPART + ((size_t)(b * 8 + z) * CONVOC + o0 + oo) * 1024 + t * 4;
        *reinterpret_cast<float4*>(&ws[off]) =
            make_float4(acc[oo][0], acc[oo][1], acc[oo][2], acc[oo][3]);
    }
}

// K2b: reduce 8 channel-chunks, apply weight-norm scale + bias, write 31x31 slice.
__global__ __launch_bounds__(256) void k_convred(const float* __restrict__ conv_b,
                                                 const float* __restrict__ ws,
                                                 float* __restrict__ out) {
    int o = blockIdx.x, b = blockIdx.y, t = threadIdx.x;
    float sc = ws[WS_SCALE + o], bi = conv_b[o];
    for (int px = t; px < 1024; px += 256) {
        float s = 0.f;
#pragma unroll
        for (int z = 0; z < 8; z++)
            s += ws[WS_CPART + ((size_t)(b * 8 + z) * CONVOC + o) * 1024 + px];
        int hh = px >> 5, ww = px & 31;
        if (hh < 31 && ww < 31)
            out[((size_t)(b * 256 + o) * 31 + hh) * 31 + ww] = sc * s + bi;
    }
}

// K3 (tiled): att[b,h,i,j] = 0.5*( qk + rel ) + 0.5*prev.
// Block = 32i x 128j tile of one (b,h).  K-tile + transposed Q-tile in LDS;
// each thread owns a 4x4 register subtile; rel via 7 diagonal rows from L1.
__global__ __launch_bounds__(256, 4) void k_att(const float* __restrict__ ws_,
                                                const float* __restrict__ prev,
                                                const float* __restrict__ rel_k,
                                                float* __restrict__ att) {
    int jt = blockIdx.x, it = blockIdx.y, bh = blockIdx.z;
    int b = bh >> 3, h = bh & 7;
    int t = threadIdx.x;
    int i0 = it * 32, j0 = jt * 128;
    __shared__ float kS[8][128];
    __shared__ float qS[32][8];
    const float* qkv = ws_ + WS_QKV;
    const float* qplane = qkv + ((size_t)b * QKVOC + h * 8) * LLEN;       // q[d][i]
    const float* kplane = qkv + ((size_t)b * QKVOC + 64 + h * 8) * LLEN;  // k[d][j]
    {   // stage K tile: 256 float4
        int d = t >> 5, jc = (t & 31) * 4;
        *reinterpret_cast<float4*>(&kS[d][jc]) =
            *reinterpret_cast<const float4*>(&kplane[(size_t)d * LLEN + j0 + jc]);
    }
    {   // stage Q tile transposed: qS[i][d]
        int i = t >> 3, d = t & 7;
        qS[i][d] = qplane[(size_t)d * LLEN + i0 + i];
    }
    __syncthreads();

    int ig = t >> 5, tj = t & 31;          // ig: i-subgroup 0..7, tj: j-group 0..31
    float qr[4][8];
#pragma unroll
    for (int ii = 0; ii < 4; ii++) {
        float4 a = *reinterpret_cast<const float4*>(&qS[ig * 4 + ii][0]);
        float4 c = *reinterpret_cast<const float4*>(&qS[ig * 4 + ii][4]);
        qr[ii][0] = a.x; qr[ii][1] = a.y; qr[ii][2] = a.z; qr[ii][3] = a.w;
        qr[ii][4] = c.x; qr[ii][5] = c.y; qr[ii][6] = c.z; qr[ii][7] = c.w;
    }
    float acc[4][4] = {};
#pragma unroll
    for (int d = 0; d < 8; d++) {
        float4 kv = *reinterpret_cast<const float4*>(&kS[d][tj * 4]);
#pragma unroll
        for (int ii = 0; ii < 4; ii++) {
            float qv = qr[ii][d];
            acc[ii][0] += qv * kv.x; acc[ii][1] += qv * kv.y;
            acc[ii][2] += qv * kv.z; acc[ii][3] += qv * kv.w;
        }
    }
    const float* rbase = rel_k + (size_t)(j0 - i0 + 1020 + 4 * (tj - ig)) * 8;
#pragma unroll
    for (int dgi = 0; dgi < 7; dgi++) {
        float4 ra = *reinterpret_cast<const float4*>(rbase + dgi * 8);
        float4 rb = *reinterpret_cast<const float4*>(rbase + dgi * 8 + 4);
#pragma unroll
        for (int ii = 0; ii < 4; ii++) {
#pragma unroll
            for (int jj = 0; jj < 4; jj++) {
                if (jj - ii + 3 == dgi) {
                    acc[ii][jj] += qr[ii][0] * ra.x + qr[ii][1] * ra.y
                                 + qr[ii][2] * ra.z + qr[ii][3] * ra.w
                                 + qr[ii][4] * rb.x + qr[ii][5] * rb.y
                                 + qr[ii][6] * rb.z + qr[ii][7] * rb.w;
                }
            }
        }
    }
#pragma unroll
    for (int ii = 0; ii < 4; ii++) {
        int i = i0 + ig * 4 + ii;
        size_t off = (((size_t)bh * 1024 + i) << 10) + j0 + tj * 4;
        float4 pv = *reinterpret_cast<const float4*>(&prev[off]);
        float4 ov;
        ov.x = 0.5f * acc[ii][0] + 0.5f * pv.x;
        ov.y = 0.5f * acc[ii][1] + 0.5f * pv.y;
        ov.z = 0.5f * acc[ii][2] + 0.5f * pv.z;
        ov.w = 0.5f * acc[ii][3] + 0.5f * pv.w;
        *reinterpret_cast<float4*>(&att[off]) = ov;
    }
}

// K4: LDS-free att-conv.  Thread (y, cg) computes 1 row x 4 cols x all 8 output
// heads.  Row data via aligned global float4 (L1/L2-hot) + 2 cross-lane shuffles
// for the +-1 column halo; edge lanes fetch the halo scalar.
__global__ __launch_bounds__(256) void k_attconv(const float* __restrict__ att,
                                                 const float* __restrict__ attc_w,
                                                 const float* __restrict__ attc_b,
                                                 float* __restrict__ ws) {
    int jt = blockIdx.x, it = blockIdx.y, b = blockIdx.z, t = threadIdx.x;
    int j0 = jt * 128, i0 = it * 8;
    int y = t >> 5, cg = t & 31;
    int orow = i0 + y;                       // output row in [0,1024)
    float acc[8][4] = {};
#pragma unroll 1
    for (int hp = 0; hp < 8; hp++) {
        const float* plane = att + (((size_t)(b * 8 + hp)) << 20);
#pragma unroll
        for (int di = 0; di < 3; di++) {
            int r = orow - 1 + di;
            bool rok = (r >= 0 && r < 1024);
            const float* rowp = plane + ((size_t)(r < 0 ? 0 : r) << 10) + j0;
            float4 v = make_float4(0.f, 0.f, 0.f, 0.f);
            if (rok) v = *reinterpret_cast<const float4*>(rowp + cg * 4);
            float ls = __shfl_up(v.w, 1, 64);
            float rs = __shfl_down(v.x, 1, 64);
            if (cg == 0)  ls = (rok && j0 > 0)            ? rowp[-1]  : 0.f;
            if (cg == 31) rs = (rok && (j0 + 128) < 1024) ? rowp[128] : 0.f;
            float w[6];
            w[0] = ls; w[1] = v.x; w[2] = v.y; w[3] = v.z; w[4] = v.w; w[5] = rs;
#pragma unroll
            for (int dj = 0; dj < 3; dj++)
#pragma unroll
                for (int ho = 0; ho < 8; ho++) {
                    float wg = attc_w[ho * 72 + hp * 9 + di * 3 + dj];
#pragma unroll
                    for (int k = 0; k < 4; k++) acc[ho][k] += wg * w[dj + k];
                }
        }
    }
    float ssum = 0.f, ssq = 0.f;
#pragma unroll
    for (int ho = 0; ho < 8; ho++) {
        float bi = attc_b[ho];
        float4 o;
        o.x = acc[ho][0] + bi; o.y = acc[ho][1] + bi;
        o.z = acc[ho][2] + bi; o.w = acc[ho][3] + bi;
        ssum += o.x + o.y + o.z + o.w;
        ssq  += o.x * o.x + o.y * o.y + o.z * o.z + o.w * o.w;
        size_t off = (((size_t)(b * 8 + ho) * 1024 + orow) << 10) + j0 + cg * 4;
        *reinterpret_cast<float4*>(&ws[WS_T + off]) = o;
    }
    for (int off = 1; off < 64; off <<= 1) {
        ssum += __shfl_xor(ssum, off, 64);
        ssq  += __shfl_xor(ssq, off, 64);
    }
    __shared__ float r1[4], r2[4];
    if ((t & 63) == 0) { r1[t >> 6] = ssum; r2[t >> 6] = ssq; }
    __syncthreads();
    if (t == 0) {
        int lin = (b * 128 + it) * 8 + jt;
        ws[WS_PART + lin * 2]     = r1[0] + r1[1] + r1[2] + r1[3];
        ws[WS_PART + lin * 2 + 1] = r2[0] + r2[1] + r2[2] + r2[3];
    }
}

// K4b: reduce partials -> per-batch mean, rstd
__global__ void k_stats(float* __restrict__ ws) {
    int b = blockIdx.x, t = threadIdx.x;
    float S = 0.f, Q = 0.f;
    for (int n = t; n < 1024; n += 256) {
        S += ws[WS_PART + (size_t)(b * 1024 + n) * 2];
        Q += ws[WS_PART + (size_t)(b * 1024 + n) * 2 + 1];
    }
    for (int off = 1; off < 64; off <<= 1) { S += __shfl_xor(S, off, 64); Q += __shfl_xor(Q, off, 64); }
    __shared__ float r1[4], r2[4];
    if ((t & 63) == 0) { r1[t >> 6] = S; r2[t >> 6] = Q; }
    __syncthreads();
    if (t == 0) {
        float Sa = r1[0] + r1[1] + r1[2] + r1[3];
        float Qa = r2[0] + r2[1] + r2[2] + r2[3];
        float N = 8.0f * 1024.f * 1024.f;
        float mean = Sa / N;
        float var = Qa / N - mean * mean;
        ws[WS_STATS + b * 2]     = mean;
        ws[WS_STATS + b * 2 + 1] = 1.0f / sqrtf(var + 1e-5f);
    }
}

// K5: per-row: normalize t + leaky + mix -> logits (in-place over att), softmax, PV -> E
__global__ __launch_bounds__(256) void k_final(float* __restrict__ logits,
                                               const float* __restrict__ gn_w,
                                               const float* __restrict__ gn_b,
                                               float* __restrict__ ws) {
    int row = blockIdx.x;                       // (b*8+h)*1024 + i
    int b = row >> 13, h = (row >> 10) & 7;
    int t = threadIdx.x;
    float mean = ws[WS_STATS + b * 2], rstd = ws[WS_STATS + b * 2 + 1];
    float gw = gn_w[h], gb = gn_b[h];
    size_t roff = (size_t)row * 1024 + t * 4;
    float4 tv = *reinterpret_cast<const float4*>(&ws[WS_T + roff]);
    float4 av = *reinterpret_cast<const float4*>(&logits[roff]);
    float lg[4];
    {
        float tt[4] = {tv.x, tv.y, tv.z, tv.w};
        float aa[4] = {av.x, av.y, av.z, av.w};
#pragma unroll
        for (int k = 0; k < 4; k++) {
            float xv = (tt[k] - mean) * rstd * gw + gb;
            xv = (xv >= 0.f) ? xv : 0.01f * xv;
            lg[k] = 0.5f * xv + 0.5f * aa[k];
        }
    }
    *reinterpret_cast<float4*>(&logits[roff]) = make_float4(lg[0], lg[1], lg[2], lg[3]);
    // softmax over the 1024-row
    float m = fmaxf(fmaxf(lg[0], lg[1]), fmaxf(lg[2], lg[3]));
    for (int off = 1; off < 64; off <<= 1) m = fmaxf(m, __shfl_xor(m, off, 64));
    __shared__ float red[4], red2[4], redE[4][8];
    int wvi = t >> 6, ln = t & 63;
    if (ln == 0) red[wvi] = m;
    __syncthreads();
    m = fmaxf(fmaxf(red[0], red[1]), fmaxf(red[2], red[3]));
    float e[4]; float s = 0.f;
#pragma unroll
    for (int k = 0; k < 4; k++) { e[k] = __expf(lg[k] - m); s += e[k]; }
    for (int off = 1; off < 64; off <<= 1) s += __shfl_xor(s, off, 64);
    if (ln == 0) red2[wvi] = s;
    __syncthreads();
    s = red2[0] + red2[1] + red2[2] + red2[3];
    // PV: E[d] = (sum_j e_j * v[d][j]) / s
    const float* vbase = ws + WS_QKV + ((size_t)b * QKVOC + 128 + h * 8) * LLEN + t * 4;
    float acc[8];
#pragma unroll
    for (int d = 0; d < 8; d++) {
        float4 vv = *reinterpret_cast<const float4*>(vbase + (size_t)d * LLEN);
        acc[d] = e[0] * vv.x + e[1] * vv.y + e[2] * vv.z + e[3] * vv.w;
    }
#pragma unroll
    for (int d = 0; d < 8; d++)
        for (int off = 1; off < 64; off <<= 1) acc[d] += __shfl_xor(acc[d], off, 64);
    if (ln == 0) {
#pragma unroll
        for (int d = 0; d < 8; d++) redE[wvi][d] = acc[d];
    }
    __syncthreads();
    if (t < 8) {
        float tot = redE[0][t] + redE[1][t] + redE[2][t] + redE[3][t];
        ws[WS_E + (size_t)row * 8 + t] = tot / s;
    }
}

// K6: scatter E -> attn output region with the reference's reshape quirk + 31x31 slice
__global__ void k_scatter(const float* __restrict__ ws, float* __restrict__ out) {
    int idx = blockIdx.x * 256 + threadIdx.x;
    if (idx >= 4 * 64 * 31 * 31) return;
    int x = idx % 31; int rest = idx / 31;
    int y = rest % 31; rest /= 31;
    int hd = rest % 64; int b = rest / 64;
    int h = hd >> 3, d = hd & 7;
    int flat = d * 1024 + y * 32 + x;
    int lp = flat >> 3, mp = flat & 7;
    float v = ws[WS_E + ((size_t)(b * 8 + h) * 1024 + lp) * 8 + mp];
    out[((size_t)(b * 256 + 192 + hd) * 31 + y) * 31 + x] = v;
}

extern "C" void kernel_launch(void* const* d_in, const int* in_sizes, int n_in,
                              void* d_out, int out_size, void* d_ws, size_t ws_size,
                              hipStream_t stream) {
    (void)in_sizes; (void)n_in; (void)out_size; (void)ws_size;
    const float* x      = (const float*)d_in[0];
    const float* prev   = (const float*)d_in[1];
    const float* conv_v = (const float*)d_in[2];
    const float* conv_g = (const float*)d_in[3];
    const float* conv_b = (const float*)d_in[4];
    const float* qkv_w  = (const float*)d_in[5];
    const float* qkv_b  = (const float*)d_in[6];
    const float* attc_w = (const float*)d_in[7];
    const float* attc_b = (const float*)d_in[8];
    const float* gn_w   = (const float*)d_in[9];
    const float* gn_b   = (const float*)d_in[10];
    const float* rel_k  = (const float*)d_in[11];
    float* out = (float*)d_out;
    float* ws  = (float*)d_ws;
    float* logits = out + 984064;   // att_matrix lives here, overwritten in-place by K5

    k_wnorm<<<192, 256, 0, stream>>>(conv_v, conv_g, ws);
    k_qkv<<<dim3(48, 4), 256, 0, stream>>>(x, qkv_w, qkv_b, ws);
    k_conv<<<dim3(48, 8, 4), 256, 0, stream>>>(x, conv_v, ws);
    k_convred<<<dim3(192, 4), 256, 0, stream>>>(conv_b, ws, out);
    k_att<<<dim3(8, 32, 32), 256, 0, stream>>>(ws, prev, rel_k, logits);
    k_attconv<<<dim3(8, 128, 4), 256, 0, stream>>>(logits, attc_w, attc_b, ws);
    k_stats<<<4, 256, 0, stream>>>(ws);
    k_final<<<32768, 256, 0, stream>>>(logits, gn_w, gn_b, ws);
    k_scatter<<<961, 256, 0, stream>>>(ws, out);
}